// Round 7
// baseline (640.534 us; speedup 1.0000x reference)
//
#include <hip/hip_runtime.h>

// ---------------------------------------------------------------------------
// GGNN on MI355X (gfx950). Runtime dtype probe: flags[0]=1 -> fp32 tensors +
// fp32 out; flags[1]=1 -> int64 edge_index. h bf16 ping-pong, agg bf16 in LDS.
//
// Round-15: LAUNCH-COUNT reduction 13 -> 7. Evidence: R4 gather replica =
// 41.5us vs ~28 real; R6 CSR pair replica = 36.6us vs ~10 real -> per-launch
// overhead ~13us, ~170us total at 13 launches. Changes:
//  1. detect_kernel folded into bucket_local (wave-parallel probes, block 0
//     writes flags; later kernels read flags as before).
//  2. prep_all folded into bucket_csr (prep section barrier-free, then csr).
//  3. gather+gru fused per layer: block owns 64 nodes; agg in LDS bf16
//     (64x72 padded, conflict-free); gru restructured to rolled jc-loop with
//     6 live accumulators (~60-80 VGPR, launch_bounds(256,6)) -- avoids R7's
//     124-VGPR occupancy trap. Race-free via h ping-pong (h0<->h1; old aggB
//     buffer is now h1). Bit-exact same arithmetic as R3.
//  4. projout folded into layer 3 (row-local after gru, same wave owns rows).
// R12/R14 measurements: T_gather ~41.5us incl gap, T_csr ~36.6us incl gaps.
// Math (linearity): segment_sum((h@Wc)[src]) == segment_sum(h[src])@Wc;
//   (agg@Wc)@W_ih^T == agg@(Wc@W_ih^T) =: agg@Wcomb (built on device).
// ---------------------------------------------------------------------------

#define DEVI __device__ __forceinline__

typedef __attribute__((ext_vector_type(8))) short short8;
typedef __attribute__((ext_vector_type(4))) short bf16x4;
typedef __attribute__((ext_vector_type(4))) float f32x4;

constexpr int N_NODES   = 100000;
constexpr int F_IN      = 256;
constexpr int H_DIM     = 64;
constexpr int C_OUT     = 40;
constexpr int ROW_TILES = N_NODES / 16;             // 6250
constexpr int CH        = 8192;                     // edges per bucket_local wg
constexpr int NBUCK     = (N_NODES + 127) / 128;    // 782 buckets of 128 nodes
constexpr int LB_STRIDE = NBUCK + 1;                // +1 sentinel (wg total)
constexpr int BCAP      = 2048;                     // max edges/bucket (mean 1534)
constexpr int LPAD      = 72;                       // LDS agg row stride (ushorts)

DEVI float bf2f(unsigned short u) {
    unsigned v = ((unsigned)u) << 16;
    float f; __builtin_memcpy(&f, &v, 4); return f;
}
DEVI unsigned short f2bf(float f) {
    unsigned u; __builtin_memcpy(&u, &f, 4);
    unsigned r = u + 0x7FFFu + ((u >> 16) & 1u);   // round-to-nearest-even
    return (unsigned short)(r >> 16);
}
DEVI float in_elem(const void* p, size_t idx, int f32flag) {
    return f32flag ? ((const float*)p)[idx]
                   : bf2f(((const unsigned short*)p)[idx]);
}
DEVI short8 f32row_to_frag(const float* __restrict__ p) {
    const f32x4* q = (const f32x4*)p;
    f32x4 lo = q[0], hi = q[1];
    short8 a;
    a[0] = (short)f2bf(lo[0]); a[1] = (short)f2bf(lo[1]);
    a[2] = (short)f2bf(lo[2]); a[3] = (short)f2bf(lo[3]);
    a[4] = (short)f2bf(hi[0]); a[5] = (short)f2bf(hi[1]);
    a[6] = (short)f2bf(hi[2]); a[7] = (short)f2bf(hi[3]);
    return a;
}

// wave-parallel dtype probes (same logic as the old detect_kernel)
DEVI int probe_i64_wave(const int* __restrict__ ei) {
    int lane = threadIdx.x & 63;
    unsigned long long m = __ballot(ei[2 * lane + 1] == 0);
    return __popcll(m) >= 63;
}
DEVI int probe_f32_wave(const void* __restrict__ x) {
    const unsigned short* u = (const unsigned short*)x;
    int lane = threadIdx.x & 63;
    int cnt = 0;
#pragma unroll
    for (int i = 0; i < 4; ++i) {
        int e = (u[lane + i * 64] >> 7) & 0xFF;
        cnt += (e >= 100 && e <= 145) ? 1 : 0;
    }
#pragma unroll
    for (int d = 1; d < 64; d <<= 1) cnt += __shfl_xor(cnt, d);
    return cnt < 230;
}

// ======================= CSR build: two-level sort =========================
__global__ __launch_bounds__(256) void bucket_local(
        const int* __restrict__ ei, int E, const void* __restrict__ x,
        int* __restrict__ wgsorted,     // [nwg*CH]  packed (ldst<<17 | src)
        int* __restrict__ lbase_g,      // [nwg*LB_STRIDE]
        int* __restrict__ flags) {
    __shared__ int hist[NBUCK];
    __shared__ int partial[256];
    __shared__ int staging[CH];
    int tid = threadIdx.x, wg = blockIdx.x;
    int i64 = probe_i64_wave(ei);       // per-wave, uniform
    if (wg == 0 && tid < 64) {
        int f32 = probe_f32_wave(x);
        if (tid == 0) { flags[0] = f32; flags[1] = i64; }
    }
    int base = wg * CH;
    int cnt_wg = min(CH, E - base);

    for (int i = tid; i < NBUCK; i += 256) hist[i] = 0;
    __syncthreads();
    for (int k = tid; k < cnt_wg; k += 256) {
        size_t e = (size_t)base + k;
        int d = i64 ? ei[2 * ((size_t)E + e)] : ei[(size_t)E + e];
        atomicAdd(&hist[d >> 7], 1);
    }
    __syncthreads();
    int i0 = 4 * tid;
    int e0 = (i0 + 0 < NBUCK) ? hist[i0 + 0] : 0;
    int e1 = (i0 + 1 < NBUCK) ? hist[i0 + 1] : 0;
    int e2 = (i0 + 2 < NBUCK) ? hist[i0 + 2] : 0;
    int e3 = (i0 + 3 < NBUCK) ? hist[i0 + 3] : 0;
    int s0 = e0, s1 = s0 + e1, s2 = s1 + e2, s3 = s2 + e3;
    __syncthreads();
    partial[tid] = s3;
    __syncthreads();
    for (int ofs = 1; ofs < 256; ofs <<= 1) {
        int add = (tid >= ofs) ? partial[tid - ofs] : 0;
        __syncthreads();
        partial[tid] += add;
        __syncthreads();
    }
    int pbase = (tid > 0) ? partial[tid - 1] : 0;
    if (i0 + 0 < NBUCK) hist[i0 + 0] = pbase;
    if (i0 + 1 < NBUCK) hist[i0 + 1] = pbase + s0;
    if (i0 + 2 < NBUCK) hist[i0 + 2] = pbase + s1;
    if (i0 + 3 < NBUCK) hist[i0 + 3] = pbase + s2;
    __syncthreads();
    int* lb = lbase_g + (size_t)wg * LB_STRIDE;
    for (int i = tid; i < NBUCK; i += 256) lb[i] = hist[i];
    if (tid == 0) lb[NBUCK] = cnt_wg;
    __syncthreads();
    for (int k = tid; k < cnt_wg; k += 256) {
        size_t e = (size_t)base + k;
        int s, d;
        if (i64) { s = ei[2 * e]; d = ei[2 * ((size_t)E + e)]; }
        else     { s = ei[e];     d = ei[(size_t)E + e]; }
        int pos = atomicAdd(&hist[d >> 7], 1);
        staging[pos] = ((d & 127) << 17) | s;     // src < 2^17
    }
    __syncthreads();
    for (int k = tid; k < cnt_wg; k += 256)
        wgsorted[(size_t)base + k] = staging[k];
}

// bucket_csr + fused weight prep (prep section is barrier-free, runs first;
// t-ranges: winfrag 16384 | wofrag 3072 | whh 12288 | b_ih 192 | b_hh 192 |
// wcomb 49152). Grid NBUCK=782 >= 318 blocks needed by prep.
__global__ __launch_bounds__(256) void bucket_csr_prep(
        const int* __restrict__ wgsorted,
        const int* __restrict__ lbase_g,
        int nwg,
        int* __restrict__ rowptr,
        int* __restrict__ counts,
        int* __restrict__ esrc,
        const void* __restrict__ w_in,
        const void* __restrict__ w_out,
        const void* __restrict__ w_hh,
        const void* __restrict__ b_ih,
        const void* __restrict__ b_hh,
        const void* __restrict__ conv_w,
        const void* __restrict__ w_ih,
        unsigned short* __restrict__ winfrag,
        unsigned short* __restrict__ wofrag,
        unsigned short* __restrict__ whh_c,
        unsigned short* __restrict__ bias_c,
        unsigned short* __restrict__ wcomb,
        const int* __restrict__ flags) {
    int tid = threadIdx.x, b = blockIdx.x;

    // ---------------- prep section (no barriers) ----------------
    {
        int f32 = flags[0];
        int t = b * 256 + tid;
        if (t < 16384) {
            int i = t & 7, lane = (t >> 3) & 63, jt = (t >> 9) & 3, kb = t >> 11;
            int k = kb * 32 + ((lane >> 4) << 3) + i;
            int col = jt * 16 + (lane & 15);
            winfrag[t] = f2bf(in_elem(w_in, (size_t)k * 64 + col, f32));
        } else if (t < 19456) {
            int u = t - 16384;
            int i = u & 7, lane = (u >> 3) & 63;
            int jt = (u >> 9) % 3, kb = u / 1536;
            int k = kb * 32 + ((lane >> 4) << 3) + i;
            int col = jt * 16 + (lane & 15);
            wofrag[u] = (col < 40) ? f2bf(in_elem(w_out, (size_t)k * 40 + col, f32))
                                   : (unsigned short)0;
        } else if (t < 31744) {
            int u = t - 19456;
            whh_c[u] = f2bf(in_elem(w_hh, u, f32));
        } else if (t < 31936) {
            int u = t - 31744;
            bias_c[u] = f2bf(in_elem(b_ih, u, f32));
        } else if (t < 32128) {
            int u = t - 31936;
            bias_c[192 + u] = f2bf(in_elem(b_hh, u, f32));
        } else if (t < 32128 + 49152) {
            int u = t - 32128;
            int l = u / 12288;
            int idx = u % 12288;
            int i = idx & 7, lane = (idx >> 3) & 63, c = idx >> 9;
            int kb = c / 12, jt = c % 12;
            int quad = lane >> 4, l15 = lane & 15;
            int k = kb * 32 + quad * 8 + i;
            int g = jt * 16 + l15;
            float acc = 0.0f;
            if (f32) {
                const f32x4* ca = (const f32x4*)((const float*)conv_w +
                                                 (size_t)l * 4096 + (size_t)k * 64);
                const f32x4* wa = (const f32x4*)((const float*)w_ih + (size_t)g * 64);
#pragma unroll
                for (int jq = 0; jq < 16; ++jq) {
                    f32x4 cv = ca[jq];
                    f32x4 wv = wa[jq];
                    acc += cv[0] * wv[0] + cv[1] * wv[1] + cv[2] * wv[2] + cv[3] * wv[3];
                }
            } else {
                const short8* ca = (const short8*)((const unsigned short*)conv_w +
                                                   (size_t)l * 4096 + (size_t)k * 64);
                const short8* wa = (const short8*)((const unsigned short*)w_ih +
                                                   (size_t)g * 64);
#pragma unroll
                for (int jq = 0; jq < 8; ++jq) {
                    short8 cv = ca[jq];
                    short8 wv = wa[jq];
#pragma unroll
                    for (int q = 0; q < 8; ++q)
                        acc += bf2f((unsigned short)cv[q]) * bf2f((unsigned short)wv[q]);
                }
            }
            wcomb[(size_t)l * 12288 + idx] = f2bf(acc);
        }
    }

    // ---------------- csr section (verbatim R3) ----------------
    __shared__ int segincl[256];
    __shared__ int segbase[256];
    __shared__ int edata[BCAP];
    __shared__ int sout[BCAP];
    __shared__ int hist2[128];
    __shared__ int cur2[128];

    int lbv = 0, cntv = 0;
    if (tid < nwg) {
        const int* lb = lbase_g + (size_t)tid * LB_STRIDE;
        lbv  = lb[b];
        cntv = lb[b + 1] - lbv;
    }
    segbase[tid] = lbv;
    segincl[tid] = cntv;
    __syncthreads();
    for (int ofs = 1; ofs < 256; ofs <<= 1) {
        int add = (tid >= ofs) ? segincl[tid - ofs] : 0;
        __syncthreads();
        segincl[tid] += add;
        __syncthreads();
    }
    int tot = min(segincl[255], BCAP);   // 13-sigma margin; clamp = visible-fail
    for (int i = tid; i < tot; i += 256) {
        int lo = 0, hi = 255;
        while (lo < hi) {
            int mid = (lo + hi) >> 1;
            if (segincl[mid] > i) hi = mid; else lo = mid + 1;
        }
        int excl = (lo > 0) ? segincl[lo - 1] : 0;
        edata[i] = wgsorted[(size_t)lo * CH + segbase[lo] + (i - excl)];
    }
    if (tid < 128) hist2[tid] = 0;
    __syncthreads();
    for (int i = tid; i < tot; i += 256) atomicAdd(&hist2[edata[i] >> 17], 1);
    __syncthreads();
    if (tid < 128) cur2[tid] = hist2[tid];
    __syncthreads();
    for (int ofs = 1; ofs < 128; ofs <<= 1) {
        int add = 0;
        if (tid < 128 && tid >= ofs) add = cur2[tid - ofs];
        __syncthreads();
        if (tid < 128) cur2[tid] += add;
        __syncthreads();
    }
    int nodeexcl = 0;
    if (tid < 128) nodeexcl = (tid > 0) ? cur2[tid - 1] : 0;
    __syncthreads();
    if (tid < 128) {
        int node = b * 128 + tid;
        if (node < N_NODES) {
            counts[node] = hist2[tid];
            rowptr[node] = b * BCAP + nodeexcl;
        }
        cur2[tid] = nodeexcl;
    }
    __syncthreads();
    for (int i = tid; i < tot; i += 256) {
        int p = edata[i];
        int pos = atomicAdd(&cur2[p >> 17], 1);
        sout[pos] = p & 0x1FFFF;
    }
    __syncthreads();
    for (int i = tid; i < tot; i += 256)
        esrc[(size_t)b * BCAP + i] = sout[i];
}

// ============================ input projection =============================
template <int XF32>
DEVI void proj_in_body(const void* __restrict__ xr,
                       const unsigned short* __restrict__ wfrag,
                       unsigned short* __restrict__ h) {
    int wid = blockIdx.x * 4 + (threadIdx.x >> 6);
    if (wid >= ROW_TILES) return;
    int lane = threadIdx.x & 63;
    int l15 = lane & 15, quad = lane >> 4;
    int row0 = wid * 16;
    int arow = row0 + l15;

    f32x4 acc[4];
#pragma unroll
    for (int jt = 0; jt < 4; ++jt) acc[jt] = (f32x4)(0.0f);

#pragma unroll
    for (int kb = 0; kb < 8; ++kb) {
        short8 a;
        if (XF32)
            a = f32row_to_frag((const float*)xr + (size_t)arow * F_IN + kb * 32 + quad * 8);
        else
            a = *(const short8*)((const unsigned short*)xr + (size_t)arow * F_IN + kb * 32 + quad * 8);
#pragma unroll
        for (int jt = 0; jt < 4; ++jt) {
            short8 b = *(const short8*)(wfrag + (size_t)((kb * 4 + jt) * 64 + lane) * 8);
            acc[jt] = __builtin_amdgcn_mfma_f32_16x16x32_bf16(a, b, acc[jt], 0, 0, 0);
        }
    }
#pragma unroll
    for (int jt = 0; jt < 4; ++jt)
#pragma unroll
        for (int r = 0; r < 4; ++r)
            h[(size_t)(row0 + quad * 4 + r) * H_DIM + jt * 16 + l15] = f2bf(acc[jt][r]);
}

__global__ __launch_bounds__(256) void proj_in_kernel(
        const void* __restrict__ x,
        const unsigned short* __restrict__ wfrag,
        unsigned short* __restrict__ h,
        const int* __restrict__ flags) {
    if (flags[0]) proj_in_body<1>(x, wfrag, h);
    else          proj_in_body<0>(x, wfrag, h);
}

// ===================== fused layer: gather + GRU (+ projout) ===============
// Block owns 64 nodes (4 waves x 16). Gather: wave w loops its 16 nodes with
// R3's 4-edge x 8B-lane layout (32 rows in flight); agg -> LDS bf16
// [64][72] (pad 8 ushorts: rows 8 banks apart -> 2-way = free).
// GRU: rolled jc-loop, 6 live f32x4 accs (~24 VGPR) to keep whole kernel
// <= 85 VGPR (launch_bounds(256,6), 24 waves/CU). h ping-pong: read hin,
// write hout (race-free vs other blocks' gather). LAST: projout fused.
template <int LAST>
__global__ __launch_bounds__(256, 6) void layer_fused(
        const unsigned short* __restrict__ hin,
        unsigned short* __restrict__ hout,
        const int* __restrict__ rowptr,
        const int* __restrict__ counts,
        const int* __restrict__ esrc,
        const unsigned short* __restrict__ wcomb_l,
        const unsigned short* __restrict__ whh_c,
        const unsigned short* __restrict__ bias_c,
        const unsigned short* __restrict__ wofrag,
        void* __restrict__ out,
        const int* __restrict__ flags) {
    __shared__ __align__(16) unsigned short lagg[64 * LPAD];  // 9 KB
    int tid = threadIdx.x;
    int w = tid >> 6, lane = tid & 63;
    int nb0 = blockIdx.x * 64;
    int sub = lane >> 4;
    int c4 = (lane & 15) * 4;

    // ---- gather phase: wave w handles nodes nb0 + w*16 + k ----
    for (int k = 0; k < 16; ++k) {
        int n = nb0 + w * 16 + k;
        if (n >= N_NODES) break;
        int start = rowptr[n];
        int deg   = counts[n];
        f32x4 acc0 = (f32x4)(0.0f), acc1 = (f32x4)(0.0f);
        for (int i = 0; i < deg; i += 32) {
            int sidx[8];
#pragma unroll
            for (int u = 0; u < 8; ++u) {
                int e = i + u * 4 + sub;
                sidx[u] = (e < deg) ? esrc[start + e] : -1;
            }
#pragma unroll
            for (int u = 0; u < 8; ++u) {
                if (sidx[u] >= 0) {
                    bf16x4 v = *(const bf16x4*)(hin + (size_t)sidx[u] * H_DIM + c4);
                    f32x4& A = (u & 1) ? acc1 : acc0;
                    A[0] += bf2f((unsigned short)v[0]);
                    A[1] += bf2f((unsigned short)v[1]);
                    A[2] += bf2f((unsigned short)v[2]);
                    A[3] += bf2f((unsigned short)v[3]);
                }
            }
        }
#pragma unroll
        for (int q = 0; q < 4; ++q) acc0[q] += acc1[q];
#pragma unroll
        for (int q = 0; q < 4; ++q) {
            acc0[q] += __shfl_xor(acc0[q], 16);
            acc0[q] += __shfl_xor(acc0[q], 32);
        }
        if (sub == 0) {
            bf16x4 o;
            o[0] = (short)f2bf(acc0[0]);
            o[1] = (short)f2bf(acc0[1]);
            o[2] = (short)f2bf(acc0[2]);
            o[3] = (short)f2bf(acc0[3]);
            *(bf16x4*)(lagg + (w * 16 + k) * LPAD + c4) = o;
        }
    }
    __syncthreads();

    // ---- GRU phase (rolled jc loop, 6 accumulators) ----
    int l15 = lane & 15, quad = lane >> 4;
    int row0 = nb0 + w * 16;
    int lrow = w * 16 + l15;
    int arow = min(row0 + l15, N_NODES - 1);

    short8 aa0 = *(const short8*)(lagg + lrow * LPAD + quad * 8);
    short8 aa1 = *(const short8*)(lagg + lrow * LPAD + 32 + quad * 8);
    short8 ah0 = *(const short8*)(hin + (size_t)arow * H_DIM + quad * 8);
    short8 ah1 = *(const short8*)(hin + (size_t)arow * H_DIM + 32 + quad * 8);

#pragma unroll 1
    for (int jc = 0; jc < 4; ++jc) {
        f32x4 ir = (f32x4)(0.0f), iz = (f32x4)(0.0f), ia = (f32x4)(0.0f);
        f32x4 hr = (f32x4)(0.0f), hz = (f32x4)(0.0f), ha = (f32x4)(0.0f);
#define WCF(kb, jt) (*(const short8*)(wcomb_l + (size_t)(((kb) * 12 + (jt)) * 64 + lane) * 8))
#define WHF(jt, kb) (*(const short8*)(whh_c + (size_t)((jt) * 16 + l15) * H_DIM + (kb) * 32 + quad * 8))
        ir = __builtin_amdgcn_mfma_f32_16x16x32_bf16(aa0, WCF(0, jc), ir, 0, 0, 0);
        iz = __builtin_amdgcn_mfma_f32_16x16x32_bf16(aa0, WCF(0, 4 + jc), iz, 0, 0, 0);
        ia = __builtin_amdgcn_mfma_f32_16x16x32_bf16(aa0, WCF(0, 8 + jc), ia, 0, 0, 0);
        hr = __builtin_amdgcn_mfma_f32_16x16x32_bf16(ah0, WHF(jc, 0), hr, 0, 0, 0);
        hz = __builtin_amdgcn_mfma_f32_16x16x32_bf16(ah0, WHF(4 + jc, 0), hz, 0, 0, 0);
        ha = __builtin_amdgcn_mfma_f32_16x16x32_bf16(ah0, WHF(8 + jc, 0), ha, 0, 0, 0);
        ir = __builtin_amdgcn_mfma_f32_16x16x32_bf16(aa1, WCF(1, jc), ir, 0, 0, 0);
        iz = __builtin_amdgcn_mfma_f32_16x16x32_bf16(aa1, WCF(1, 4 + jc), iz, 0, 0, 0);
        ia = __builtin_amdgcn_mfma_f32_16x16x32_bf16(aa1, WCF(1, 8 + jc), ia, 0, 0, 0);
        hr = __builtin_amdgcn_mfma_f32_16x16x32_bf16(ah1, WHF(jc, 1), hr, 0, 0, 0);
        hz = __builtin_amdgcn_mfma_f32_16x16x32_bf16(ah1, WHF(4 + jc, 1), hz, 0, 0, 0);
        ha = __builtin_amdgcn_mfma_f32_16x16x32_bf16(ah1, WHF(8 + jc, 1), ha, 0, 0, 0);
#undef WCF
#undef WHF
        int j = jc * 16 + l15;
        float bir = bf2f(bias_c[j]),       bhr = bf2f(bias_c[192 + j]);
        float biz = bf2f(bias_c[64 + j]),  bhz = bf2f(bias_c[256 + j]);
        float bin = bf2f(bias_c[128 + j]), bhn = bf2f(bias_c[320 + j]);
#pragma unroll
        for (int r = 0; r < 4; ++r) {
            int row = row0 + quad * 4 + r;
            if (row < N_NODES) {
                float xr = (ir[r] + bir) + (hr[r] + bhr);
                float xz = (iz[r] + biz) + (hz[r] + bhz);
                float in_ = ia[r] + bin;
                float hn_ = ha[r] + bhn;
                xr = fminf(fmaxf(xr, -30.0f), 30.0f);
                xz = fminf(fmaxf(xz, -30.0f), 30.0f);
                float rg = 1.0f / (1.0f + __expf(-xr));
                float zg = 1.0f / (1.0f + __expf(-xz));
                float na = in_ + rg * hn_;
                float ey = __expf(-2.0f * fabsf(na));          // (0,1] — safe tanh
                float th = (1.0f - ey) / (1.0f + ey);
                float nt = (na < 0.0f) ? -th : th;
                float ho = bf2f(hin[(size_t)row * H_DIM + j]);
                hout[(size_t)row * H_DIM + j] = f2bf((1.0f - zg) * nt + zg * ho);
            }
        }
    }

    // ---- projout phase (LAST only; row-local, same wave owns rows) ----
    if (LAST) {
        int f32out = flags[0];
        f32x4 pacc[3];
#pragma unroll
        for (int jt = 0; jt < 3; ++jt) pacc[jt] = (f32x4)(0.0f);
#pragma unroll
        for (int kb = 0; kb < 2; ++kb) {
            short8 a = *(const short8*)(hout + (size_t)arow * H_DIM + kb * 32 + quad * 8);
#pragma unroll
            for (int jt = 0; jt < 3; ++jt) {
                short8 bfr = *(const short8*)(wofrag + (size_t)((kb * 3 + jt) * 64 + lane) * 8);
                pacc[jt] = __builtin_amdgcn_mfma_f32_16x16x32_bf16(a, bfr, pacc[jt], 0, 0, 0);
            }
        }
        float* of = (float*)out;
        unsigned short* ob = (unsigned short*)out;
        bool valid2 = (l15 < 8);
#pragma unroll
        for (int r = 0; r < 4; ++r) {
            int row = row0 + quad * 4 + r;
            float v0 = pacc[0][r], v1 = pacc[1][r], v2 = pacc[2][r];
            float mx = fmaxf(v0, v1);
            if (valid2) mx = fmaxf(mx, v2);
#pragma unroll
            for (int d = 1; d < 16; d <<= 1) mx = fmaxf(mx, __shfl_xor(mx, d));
            float s = __expf(v0 - mx) + __expf(v1 - mx) + (valid2 ? __expf(v2 - mx) : 0.0f);
#pragma unroll
            for (int d = 1; d < 16; d <<= 1) s += __shfl_xor(s, d);
            float lg = mx + __logf(s);
            if (row < N_NODES) {
                size_t o0 = (size_t)row * C_OUT + l15;
                if (f32out) {
                    of[o0]      = v0 - lg;
                    of[o0 + 16] = v1 - lg;
                    if (valid2) of[o0 + 32] = v2 - lg;
                } else {
                    ob[o0]      = f2bf(v0 - lg);
                    ob[o0 + 16] = f2bf(v1 - lg);
                    if (valid2) ob[o0 + 32] = f2bf(v2 - lg);
                }
            }
        }
    }
}

// ---------------------------------------------------------------------------
extern "C" void kernel_launch(void* const* d_in, const int* in_sizes, int n_in,
                              void* d_out, int out_size, void* d_ws, size_t ws_size,
                              hipStream_t stream) {
    const void* x      = d_in[0];
    const int*  ei     = (const int*)d_in[1];
    const void* w_in   = d_in[2];
    const void* w_out  = d_in[3];
    const void* conv_w = d_in[4];
    const void* w_ih   = d_in[5];
    const void* w_hh   = d_in[6];
    const void* b_ih   = d_in[7];
    const void* b_hh   = d_in[8];

    const int E   = in_sizes[1] / 2;
    const int nwg = (E + CH - 1) / CH;   // 147 for E=1.2M (<= 256 required)

    // workspace carve-up (256B aligned). Total ~38.4 MB.
    char* ws = (char*)d_ws;
    size_t off = 0;
    auto carve = [&](size_t bytes) {
        void* p = ws + off;
        off += (bytes + 255) & ~(size_t)255;
        return p;
    };
    int*            flags    = (int*)carve(256);
    unsigned short* h1       = (unsigned short*)carve((size_t)N_NODES * H_DIM * 2); // 12.8 MB
    unsigned short* h0       = (unsigned short*)carve((size_t)N_NODES * H_DIM * 2); // 12.8 MB
    int*            counts   = (int*)carve((size_t)N_NODES * 4);
    int*            rowptr   = (int*)carve((size_t)N_NODES * 4);
    int*            wgsorted = (int*)carve((size_t)nwg * CH * 4);                   // 4.8 MB
    int*            lbase_g  = (int*)carve((size_t)nwg * LB_STRIDE * 4);            // 0.46 MB
    int*            esrcP    = (int*)carve((size_t)NBUCK * BCAP * 4);               // 6.4 MB
    unsigned short* winfrag  = (unsigned short*)carve((size_t)16384 * 2);
    unsigned short* wcomb    = (unsigned short*)carve((size_t)4 * 12288 * 2);
    unsigned short* wofrag   = (unsigned short*)carve((size_t)3072 * 2);
    unsigned short* whh_c    = (unsigned short*)carve((size_t)12288 * 2);
    unsigned short* bias_c   = (unsigned short*)carve((size_t)384 * 2);

    // ---- CSR build (kernel 1 also probes dtypes, writes flags) ----
    bucket_local<<<nwg, 256, 0, stream>>>(ei, E, x, wgsorted, lbase_g, flags);
    bucket_csr_prep<<<NBUCK, 256, 0, stream>>>(
        wgsorted, lbase_g, nwg, rowptr, counts, esrcP,
        w_in, w_out, w_hh, b_ih, b_hh, conv_w, w_ih,
        winfrag, wofrag, whh_c, bias_c, wcomb, flags);

    const int gblocks = (ROW_TILES + 3) / 4;  // 1563

    // ---- input projection -> h0 ----
    proj_in_kernel<<<gblocks, 256, 0, stream>>>(x, winfrag, h0, flags);

    // ---- GGNN layers, h ping-pong (h0 -> h1 -> h0 -> h1 -> h0) ----
    layer_fused<0><<<gblocks, 256, 0, stream>>>(h0, h1, rowptr, counts, esrcP,
        wcomb + 0 * 12288, whh_c, bias_c, wofrag, d_out, flags);
    layer_fused<0><<<gblocks, 256, 0, stream>>>(h1, h0, rowptr, counts, esrcP,
        wcomb + 1 * 12288, whh_c, bias_c, wofrag, d_out, flags);
    layer_fused<0><<<gblocks, 256, 0, stream>>>(h0, h1, rowptr, counts, esrcP,
        wcomb + 2 * 12288, whh_c, bias_c, wofrag, d_out, flags);
    layer_fused<1><<<gblocks, 256, 0, stream>>>(h1, h0, rowptr, counts, esrcP,
        wcomb + 3 * 12288, whh_c, bias_c, wofrag, d_out, flags);
}

// Round 8
// 544.204 us; speedup vs baseline: 1.1770x; 1.1770x over previous
//
#include <hip/hip_runtime.h>

// ---------------------------------------------------------------------------
// GGNN on MI355X (gfx950). Runtime dtype probe: flags[0]=1 -> fp32 tensors +
// fp32 out; flags[1]=1 -> int64 edge_index. h bf16 ping-pong, agg bf16 in LDS.
//
// Round-16: fix R15's grid starvation. R15 counters: layer_fused 117us x4 =
// 73% of total, Occupancy 41% (grid-limited: 1563 blocks = 6 waves/SIMD
// available), HBM 12%, Mfma 2% -> latency-bound gather with 16x fewer waves
// than R3's standalone gather (~35us real). Fix: 16 nodes/block -> 6250
// blocks = 24 waves/SIMD available; gather = wave handles 4 nodes serially
// (same 32-rows-in-flight batch); GRU column-split: wave w computes output
// cols [16w,16w+16) for the block's 16 rows (columns partition -> no
// cross-wave reduce). LAST: h_new kept in LDS only (skip 12.8MB global
// write), wave 0 does projout from LDS. Launches stay at 7.
// R15 kept: detect->bucket_local, prep->bucket_csr fusions, h ping-pong.
// Measurements: R4 T_gather~41.5us incl gap; R6 T_csr-pair~36.6 incl gaps.
// Math (linearity): segment_sum((h@Wc)[src]) == segment_sum(h[src])@Wc;
//   (agg@Wc)@W_ih^T == agg@(Wc@W_ih^T) =: agg@Wcomb (built on device).
// ---------------------------------------------------------------------------

#define DEVI __device__ __forceinline__

typedef __attribute__((ext_vector_type(8))) short short8;
typedef __attribute__((ext_vector_type(4))) short bf16x4;
typedef __attribute__((ext_vector_type(4))) float f32x4;

constexpr int N_NODES   = 100000;
constexpr int F_IN      = 256;
constexpr int H_DIM     = 64;
constexpr int C_OUT     = 40;
constexpr int ROW_TILES = N_NODES / 16;             // 6250
constexpr int CH        = 8192;                     // edges per bucket_local wg
constexpr int NBUCK     = (N_NODES + 127) / 128;    // 782 buckets of 128 nodes
constexpr int LB_STRIDE = NBUCK + 1;                // +1 sentinel (wg total)
constexpr int BCAP      = 2048;                     // max edges/bucket (mean 1534)
constexpr int LPAD      = 72;                       // LDS row stride (ushorts)

DEVI float bf2f(unsigned short u) {
    unsigned v = ((unsigned)u) << 16;
    float f; __builtin_memcpy(&f, &v, 4); return f;
}
DEVI unsigned short f2bf(float f) {
    unsigned u; __builtin_memcpy(&u, &f, 4);
    unsigned r = u + 0x7FFFu + ((u >> 16) & 1u);   // round-to-nearest-even
    return (unsigned short)(r >> 16);
}
DEVI float in_elem(const void* p, size_t idx, int f32flag) {
    return f32flag ? ((const float*)p)[idx]
                   : bf2f(((const unsigned short*)p)[idx]);
}
DEVI short8 f32row_to_frag(const float* __restrict__ p) {
    const f32x4* q = (const f32x4*)p;
    f32x4 lo = q[0], hi = q[1];
    short8 a;
    a[0] = (short)f2bf(lo[0]); a[1] = (short)f2bf(lo[1]);
    a[2] = (short)f2bf(lo[2]); a[3] = (short)f2bf(lo[3]);
    a[4] = (short)f2bf(hi[0]); a[5] = (short)f2bf(hi[1]);
    a[6] = (short)f2bf(hi[2]); a[7] = (short)f2bf(hi[3]);
    return a;
}

// wave-parallel dtype probes (same logic as the old detect_kernel)
DEVI int probe_i64_wave(const int* __restrict__ ei) {
    int lane = threadIdx.x & 63;
    unsigned long long m = __ballot(ei[2 * lane + 1] == 0);
    return __popcll(m) >= 63;
}
DEVI int probe_f32_wave(const void* __restrict__ x) {
    const unsigned short* u = (const unsigned short*)x;
    int lane = threadIdx.x & 63;
    int cnt = 0;
#pragma unroll
    for (int i = 0; i < 4; ++i) {
        int e = (u[lane + i * 64] >> 7) & 0xFF;
        cnt += (e >= 100 && e <= 145) ? 1 : 0;
    }
#pragma unroll
    for (int d = 1; d < 64; d <<= 1) cnt += __shfl_xor(cnt, d);
    return cnt < 230;
}

// ======================= CSR build: two-level sort =========================
__global__ __launch_bounds__(256) void bucket_local(
        const int* __restrict__ ei, int E, const void* __restrict__ x,
        int* __restrict__ wgsorted,     // [nwg*CH]  packed (ldst<<17 | src)
        int* __restrict__ lbase_g,      // [nwg*LB_STRIDE]
        int* __restrict__ flags) {
    __shared__ int hist[NBUCK];
    __shared__ int partial[256];
    __shared__ int staging[CH];
    int tid = threadIdx.x, wg = blockIdx.x;
    int i64 = probe_i64_wave(ei);       // per-wave, uniform
    if (wg == 0 && tid < 64) {
        int f32 = probe_f32_wave(x);
        if (tid == 0) { flags[0] = f32; flags[1] = i64; }
    }
    int base = wg * CH;
    int cnt_wg = min(CH, E - base);

    for (int i = tid; i < NBUCK; i += 256) hist[i] = 0;
    __syncthreads();
    for (int k = tid; k < cnt_wg; k += 256) {
        size_t e = (size_t)base + k;
        int d = i64 ? ei[2 * ((size_t)E + e)] : ei[(size_t)E + e];
        atomicAdd(&hist[d >> 7], 1);
    }
    __syncthreads();
    int i0 = 4 * tid;
    int e0 = (i0 + 0 < NBUCK) ? hist[i0 + 0] : 0;
    int e1 = (i0 + 1 < NBUCK) ? hist[i0 + 1] : 0;
    int e2 = (i0 + 2 < NBUCK) ? hist[i0 + 2] : 0;
    int e3 = (i0 + 3 < NBUCK) ? hist[i0 + 3] : 0;
    int s0 = e0, s1 = s0 + e1, s2 = s1 + e2, s3 = s2 + e3;
    __syncthreads();
    partial[tid] = s3;
    __syncthreads();
    for (int ofs = 1; ofs < 256; ofs <<= 1) {
        int add = (tid >= ofs) ? partial[tid - ofs] : 0;
        __syncthreads();
        partial[tid] += add;
        __syncthreads();
    }
    int pbase = (tid > 0) ? partial[tid - 1] : 0;
    if (i0 + 0 < NBUCK) hist[i0 + 0] = pbase;
    if (i0 + 1 < NBUCK) hist[i0 + 1] = pbase + s0;
    if (i0 + 2 < NBUCK) hist[i0 + 2] = pbase + s1;
    if (i0 + 3 < NBUCK) hist[i0 + 3] = pbase + s2;
    __syncthreads();
    int* lb = lbase_g + (size_t)wg * LB_STRIDE;
    for (int i = tid; i < NBUCK; i += 256) lb[i] = hist[i];
    if (tid == 0) lb[NBUCK] = cnt_wg;
    __syncthreads();
    for (int k = tid; k < cnt_wg; k += 256) {
        size_t e = (size_t)base + k;
        int s, d;
        if (i64) { s = ei[2 * e]; d = ei[2 * ((size_t)E + e)]; }
        else     { s = ei[e];     d = ei[(size_t)E + e]; }
        int pos = atomicAdd(&hist[d >> 7], 1);
        staging[pos] = ((d & 127) << 17) | s;     // src < 2^17
    }
    __syncthreads();
    for (int k = tid; k < cnt_wg; k += 256)
        wgsorted[(size_t)base + k] = staging[k];
}

// bucket_csr + fused weight prep (prep section barrier-free, runs first;
// t-ranges: winfrag 16384 | wofrag 3072 | whh 12288 | b_ih 192 | b_hh 192 |
// wcomb 49152). Grid NBUCK=782 >= 318 blocks needed by prep.
__global__ __launch_bounds__(256) void bucket_csr_prep(
        const int* __restrict__ wgsorted,
        const int* __restrict__ lbase_g,
        int nwg,
        int* __restrict__ rowptr,
        int* __restrict__ counts,
        int* __restrict__ esrc,
        const void* __restrict__ w_in,
        const void* __restrict__ w_out,
        const void* __restrict__ w_hh,
        const void* __restrict__ b_ih,
        const void* __restrict__ b_hh,
        const void* __restrict__ conv_w,
        const void* __restrict__ w_ih,
        unsigned short* __restrict__ winfrag,
        unsigned short* __restrict__ wofrag,
        unsigned short* __restrict__ whh_c,
        unsigned short* __restrict__ bias_c,
        unsigned short* __restrict__ wcomb,
        const int* __restrict__ flags) {
    int tid = threadIdx.x, b = blockIdx.x;

    // ---------------- prep section (no barriers) ----------------
    {
        int f32 = flags[0];
        int t = b * 256 + tid;
        if (t < 16384) {
            int i = t & 7, lane = (t >> 3) & 63, jt = (t >> 9) & 3, kb = t >> 11;
            int k = kb * 32 + ((lane >> 4) << 3) + i;
            int col = jt * 16 + (lane & 15);
            winfrag[t] = f2bf(in_elem(w_in, (size_t)k * 64 + col, f32));
        } else if (t < 19456) {
            int u = t - 16384;
            int i = u & 7, lane = (u >> 3) & 63;
            int jt = (u >> 9) % 3, kb = u / 1536;
            int k = kb * 32 + ((lane >> 4) << 3) + i;
            int col = jt * 16 + (lane & 15);
            wofrag[u] = (col < 40) ? f2bf(in_elem(w_out, (size_t)k * 40 + col, f32))
                                   : (unsigned short)0;
        } else if (t < 31744) {
            int u = t - 19456;
            whh_c[u] = f2bf(in_elem(w_hh, u, f32));
        } else if (t < 31936) {
            int u = t - 31744;
            bias_c[u] = f2bf(in_elem(b_ih, u, f32));
        } else if (t < 32128) {
            int u = t - 31936;
            bias_c[192 + u] = f2bf(in_elem(b_hh, u, f32));
        } else if (t < 32128 + 49152) {
            int u = t - 32128;
            int l = u / 12288;
            int idx = u % 12288;
            int i = idx & 7, lane = (idx >> 3) & 63, c = idx >> 9;
            int kb = c / 12, jt = c % 12;
            int quad = lane >> 4, l15 = lane & 15;
            int k = kb * 32 + quad * 8 + i;
            int g = jt * 16 + l15;
            float acc = 0.0f;
            if (f32) {
                const f32x4* ca = (const f32x4*)((const float*)conv_w +
                                                 (size_t)l * 4096 + (size_t)k * 64);
                const f32x4* wa = (const f32x4*)((const float*)w_ih + (size_t)g * 64);
#pragma unroll
                for (int jq = 0; jq < 16; ++jq) {
                    f32x4 cv = ca[jq];
                    f32x4 wv = wa[jq];
                    acc += cv[0] * wv[0] + cv[1] * wv[1] + cv[2] * wv[2] + cv[3] * wv[3];
                }
            } else {
                const short8* ca = (const short8*)((const unsigned short*)conv_w +
                                                   (size_t)l * 4096 + (size_t)k * 64);
                const short8* wa = (const short8*)((const unsigned short*)w_ih +
                                                   (size_t)g * 64);
#pragma unroll
                for (int jq = 0; jq < 8; ++jq) {
                    short8 cv = ca[jq];
                    short8 wv = wa[jq];
#pragma unroll
                    for (int q = 0; q < 8; ++q)
                        acc += bf2f((unsigned short)cv[q]) * bf2f((unsigned short)wv[q]);
                }
            }
            wcomb[(size_t)l * 12288 + idx] = f2bf(acc);
        }
    }

    // ---------------- csr section (verbatim R3) ----------------
    __shared__ int segincl[256];
    __shared__ int segbase[256];
    __shared__ int edata[BCAP];
    __shared__ int sout[BCAP];
    __shared__ int hist2[128];
    __shared__ int cur2[128];

    int lbv = 0, cntv = 0;
    if (tid < nwg) {
        const int* lb = lbase_g + (size_t)tid * LB_STRIDE;
        lbv  = lb[b];
        cntv = lb[b + 1] - lbv;
    }
    segbase[tid] = lbv;
    segincl[tid] = cntv;
    __syncthreads();
    for (int ofs = 1; ofs < 256; ofs <<= 1) {
        int add = (tid >= ofs) ? segincl[tid - ofs] : 0;
        __syncthreads();
        segincl[tid] += add;
        __syncthreads();
    }
    int tot = min(segincl[255], BCAP);   // 13-sigma margin; clamp = visible-fail
    for (int i = tid; i < tot; i += 256) {
        int lo = 0, hi = 255;
        while (lo < hi) {
            int mid = (lo + hi) >> 1;
            if (segincl[mid] > i) hi = mid; else lo = mid + 1;
        }
        int excl = (lo > 0) ? segincl[lo - 1] : 0;
        edata[i] = wgsorted[(size_t)lo * CH + segbase[lo] + (i - excl)];
    }
    if (tid < 128) hist2[tid] = 0;
    __syncthreads();
    for (int i = tid; i < tot; i += 256) atomicAdd(&hist2[edata[i] >> 17], 1);
    __syncthreads();
    if (tid < 128) cur2[tid] = hist2[tid];
    __syncthreads();
    for (int ofs = 1; ofs < 128; ofs <<= 1) {
        int add = 0;
        if (tid < 128 && tid >= ofs) add = cur2[tid - ofs];
        __syncthreads();
        if (tid < 128) cur2[tid] += add;
        __syncthreads();
    }
    int nodeexcl = 0;
    if (tid < 128) nodeexcl = (tid > 0) ? cur2[tid - 1] : 0;
    __syncthreads();
    if (tid < 128) {
        int node = b * 128 + tid;
        if (node < N_NODES) {
            counts[node] = hist2[tid];
            rowptr[node] = b * BCAP + nodeexcl;
        }
        cur2[tid] = nodeexcl;
    }
    __syncthreads();
    for (int i = tid; i < tot; i += 256) {
        int p = edata[i];
        int pos = atomicAdd(&cur2[p >> 17], 1);
        sout[pos] = p & 0x1FFFF;
    }
    __syncthreads();
    for (int i = tid; i < tot; i += 256)
        esrc[(size_t)b * BCAP + i] = sout[i];
}

// ============================ input projection =============================
template <int XF32>
DEVI void proj_in_body(const void* __restrict__ xr,
                       const unsigned short* __restrict__ wfrag,
                       unsigned short* __restrict__ h) {
    int wid = blockIdx.x * 4 + (threadIdx.x >> 6);
    if (wid >= ROW_TILES) return;
    int lane = threadIdx.x & 63;
    int l15 = lane & 15, quad = lane >> 4;
    int row0 = wid * 16;
    int arow = row0 + l15;

    f32x4 acc[4];
#pragma unroll
    for (int jt = 0; jt < 4; ++jt) acc[jt] = (f32x4)(0.0f);

#pragma unroll
    for (int kb = 0; kb < 8; ++kb) {
        short8 a;
        if (XF32)
            a = f32row_to_frag((const float*)xr + (size_t)arow * F_IN + kb * 32 + quad * 8);
        else
            a = *(const short8*)((const unsigned short*)xr + (size_t)arow * F_IN + kb * 32 + quad * 8);
#pragma unroll
        for (int jt = 0; jt < 4; ++jt) {
            short8 b = *(const short8*)(wfrag + (size_t)((kb * 4 + jt) * 64 + lane) * 8);
            acc[jt] = __builtin_amdgcn_mfma_f32_16x16x32_bf16(a, b, acc[jt], 0, 0, 0);
        }
    }
#pragma unroll
    for (int jt = 0; jt < 4; ++jt)
#pragma unroll
        for (int r = 0; r < 4; ++r)
            h[(size_t)(row0 + quad * 4 + r) * H_DIM + jt * 16 + l15] = f2bf(acc[jt][r]);
}

__global__ __launch_bounds__(256) void proj_in_kernel(
        const void* __restrict__ x,
        const unsigned short* __restrict__ wfrag,
        unsigned short* __restrict__ h,
        const int* __restrict__ flags) {
    if (flags[0]) proj_in_body<1>(x, wfrag, h);
    else          proj_in_body<0>(x, wfrag, h);
}

// ===================== fused layer: gather + GRU (+ projout) ===============
// Block owns 16 nodes; grid 6250 blocks = 25000 waves (24/SIMD available).
// Gather: wave w handles nodes nb0+w*4+k (k=0..3) with the 4-edge x 8B-lane
// layout (32 rows in flight). agg -> LDS bf16 [16][72].
// GRU: all 4 waves process the SAME 16 rows; wave w computes output columns
// [16w, 16w+16) (jc = w) -- columns partition, no cross-wave reduction.
// LAST: h_new stays in LDS (no global h write); wave 0 does projout.
template <int LAST>
__global__ __launch_bounds__(256, 6) void layer_fused(
        const unsigned short* __restrict__ hin,
        unsigned short* __restrict__ hout,
        const int* __restrict__ rowptr,
        const int* __restrict__ counts,
        const int* __restrict__ esrc,
        const unsigned short* __restrict__ wcomb_l,
        const unsigned short* __restrict__ whh_c,
        const unsigned short* __restrict__ bias_c,
        const unsigned short* __restrict__ wofrag,
        void* __restrict__ out,
        const int* __restrict__ flags) {
    __shared__ __align__(16) unsigned short lagg[16 * LPAD];   // 2.25 KB
    __shared__ __align__(16) unsigned short hnew[16 * LPAD];   // 2.25 KB (LAST)
    int tid = threadIdx.x;
    int w = tid >> 6, lane = tid & 63;
    int nb0 = blockIdx.x * 16;
    int sub = lane >> 4;
    int c4 = (lane & 15) * 4;

    // ---- gather phase: wave w handles nodes nb0 + w*4 + k ----
#pragma unroll 1
    for (int k = 0; k < 4; ++k) {
        int n = nb0 + w * 4 + k;           // always < N_NODES (6250*16 = 100000)
        int start = rowptr[n];
        int deg   = counts[n];
        f32x4 acc0 = (f32x4)(0.0f), acc1 = (f32x4)(0.0f);
        for (int i = 0; i < deg; i += 32) {
            int sidx[8];
#pragma unroll
            for (int u = 0; u < 8; ++u) {
                int e = i + u * 4 + sub;
                sidx[u] = (e < deg) ? esrc[start + e] : -1;
            }
#pragma unroll
            for (int u = 0; u < 8; ++u) {
                if (sidx[u] >= 0) {
                    bf16x4 v = *(const bf16x4*)(hin + (size_t)sidx[u] * H_DIM + c4);
                    f32x4& A = (u & 1) ? acc1 : acc0;
                    A[0] += bf2f((unsigned short)v[0]);
                    A[1] += bf2f((unsigned short)v[1]);
                    A[2] += bf2f((unsigned short)v[2]);
                    A[3] += bf2f((unsigned short)v[3]);
                }
            }
        }
#pragma unroll
        for (int q = 0; q < 4; ++q) acc0[q] += acc1[q];
#pragma unroll
        for (int q = 0; q < 4; ++q) {
            acc0[q] += __shfl_xor(acc0[q], 16);
            acc0[q] += __shfl_xor(acc0[q], 32);
        }
        if (sub == 0) {
            bf16x4 o;
            o[0] = (short)f2bf(acc0[0]);
            o[1] = (short)f2bf(acc0[1]);
            o[2] = (short)f2bf(acc0[2]);
            o[3] = (short)f2bf(acc0[3]);
            *(bf16x4*)(lagg + (w * 4 + k) * LPAD + c4) = o;
        }
    }
    __syncthreads();

    // ---- GRU phase: wave w computes columns jc = w for the 16 rows ----
    int l15 = lane & 15, quad = lane >> 4;
    int arow = nb0 + l15;
    int jc = w;

    short8 aa0 = *(const short8*)(lagg + l15 * LPAD + quad * 8);
    short8 aa1 = *(const short8*)(lagg + l15 * LPAD + 32 + quad * 8);
    short8 ah0 = *(const short8*)(hin + (size_t)arow * H_DIM + quad * 8);
    short8 ah1 = *(const short8*)(hin + (size_t)arow * H_DIM + 32 + quad * 8);

    {
        f32x4 ir = (f32x4)(0.0f), iz = (f32x4)(0.0f), ia = (f32x4)(0.0f);
        f32x4 hr = (f32x4)(0.0f), hz = (f32x4)(0.0f), ha = (f32x4)(0.0f);
#define WCF(kb, jt) (*(const short8*)(wcomb_l + (size_t)(((kb) * 12 + (jt)) * 64 + lane) * 8))
#define WHF(jt, kb) (*(const short8*)(whh_c + (size_t)((jt) * 16 + l15) * H_DIM + (kb) * 32 + quad * 8))
        ir = __builtin_amdgcn_mfma_f32_16x16x32_bf16(aa0, WCF(0, jc), ir, 0, 0, 0);
        iz = __builtin_amdgcn_mfma_f32_16x16x32_bf16(aa0, WCF(0, 4 + jc), iz, 0, 0, 0);
        ia = __builtin_amdgcn_mfma_f32_16x16x32_bf16(aa0, WCF(0, 8 + jc), ia, 0, 0, 0);
        hr = __builtin_amdgcn_mfma_f32_16x16x32_bf16(ah0, WHF(jc, 0), hr, 0, 0, 0);
        hz = __builtin_amdgcn_mfma_f32_16x16x32_bf16(ah0, WHF(4 + jc, 0), hz, 0, 0, 0);
        ha = __builtin_amdgcn_mfma_f32_16x16x32_bf16(ah0, WHF(8 + jc, 0), ha, 0, 0, 0);
        ir = __builtin_amdgcn_mfma_f32_16x16x32_bf16(aa1, WCF(1, jc), ir, 0, 0, 0);
        iz = __builtin_amdgcn_mfma_f32_16x16x32_bf16(aa1, WCF(1, 4 + jc), iz, 0, 0, 0);
        ia = __builtin_amdgcn_mfma_f32_16x16x32_bf16(aa1, WCF(1, 8 + jc), ia, 0, 0, 0);
        hr = __builtin_amdgcn_mfma_f32_16x16x32_bf16(ah1, WHF(jc, 1), hr, 0, 0, 0);
        hz = __builtin_amdgcn_mfma_f32_16x16x32_bf16(ah1, WHF(4 + jc, 1), hz, 0, 0, 0);
        ha = __builtin_amdgcn_mfma_f32_16x16x32_bf16(ah1, WHF(8 + jc, 1), ha, 0, 0, 0);
#undef WCF
#undef WHF
        int j = jc * 16 + l15;
        float bir = bf2f(bias_c[j]),       bhr = bf2f(bias_c[192 + j]);
        float biz = bf2f(bias_c[64 + j]),  bhz = bf2f(bias_c[256 + j]);
        float bin = bf2f(bias_c[128 + j]), bhn = bf2f(bias_c[320 + j]);
#pragma unroll
        for (int r = 0; r < 4; ++r) {
            int row = nb0 + quad * 4 + r;
            float xr = (ir[r] + bir) + (hr[r] + bhr);
            float xz = (iz[r] + biz) + (hz[r] + bhz);
            float in_ = ia[r] + bin;
            float hn_ = ha[r] + bhn;
            xr = fminf(fmaxf(xr, -30.0f), 30.0f);
            xz = fminf(fmaxf(xz, -30.0f), 30.0f);
            float rg = 1.0f / (1.0f + __expf(-xr));
            float zg = 1.0f / (1.0f + __expf(-xz));
            float na = in_ + rg * hn_;
            float ey = __expf(-2.0f * fabsf(na));          // (0,1] — safe tanh
            float th = (1.0f - ey) / (1.0f + ey);
            float nt = (na < 0.0f) ? -th : th;
            float ho = bf2f(hin[(size_t)row * H_DIM + j]);
            unsigned short hv = f2bf((1.0f - zg) * nt + zg * ho);
            if (LAST) hnew[(quad * 4 + r) * LPAD + j] = hv;
            else      hout[(size_t)row * H_DIM + j] = hv;
        }
    }

    // ---- projout phase (LAST only; wave 0 handles the block's 16 rows) ----
    if (LAST) {
        __syncthreads();
        if (w == 0) {
            int f32out = flags[0];
            f32x4 pacc[3];
#pragma unroll
            for (int jt = 0; jt < 3; ++jt) pacc[jt] = (f32x4)(0.0f);
#pragma unroll
            for (int kb = 0; kb < 2; ++kb) {
                short8 a = *(const short8*)(hnew + l15 * LPAD + kb * 32 + quad * 8);
#pragma unroll
                for (int jt = 0; jt < 3; ++jt) {
                    short8 bfr = *(const short8*)(wofrag + (size_t)((kb * 3 + jt) * 64 + lane) * 8);
                    pacc[jt] = __builtin_amdgcn_mfma_f32_16x16x32_bf16(a, bfr, pacc[jt], 0, 0, 0);
                }
            }
            float* of = (float*)out;
            unsigned short* ob = (unsigned short*)out;
            bool valid2 = (l15 < 8);
#pragma unroll
            for (int r = 0; r < 4; ++r) {
                int row = nb0 + quad * 4 + r;
                float v0 = pacc[0][r], v1 = pacc[1][r], v2 = pacc[2][r];
                float mx = fmaxf(v0, v1);
                if (valid2) mx = fmaxf(mx, v2);
#pragma unroll
                for (int d = 1; d < 16; d <<= 1) mx = fmaxf(mx, __shfl_xor(mx, d));
                float s = __expf(v0 - mx) + __expf(v1 - mx) + (valid2 ? __expf(v2 - mx) : 0.0f);
#pragma unroll
                for (int d = 1; d < 16; d <<= 1) s += __shfl_xor(s, d);
                float lg = mx + __logf(s);
                size_t o0 = (size_t)row * C_OUT + l15;
                if (f32out) {
                    of[o0]      = v0 - lg;
                    of[o0 + 16] = v1 - lg;
                    if (valid2) of[o0 + 32] = v2 - lg;
                } else {
                    ob[o0]      = f2bf(v0 - lg);
                    ob[o0 + 16] = f2bf(v1 - lg);
                    if (valid2) ob[o0 + 32] = f2bf(v2 - lg);
                }
            }
        }
    }
}

// ---------------------------------------------------------------------------
extern "C" void kernel_launch(void* const* d_in, const int* in_sizes, int n_in,
                              void* d_out, int out_size, void* d_ws, size_t ws_size,
                              hipStream_t stream) {
    const void* x      = d_in[0];
    const int*  ei     = (const int*)d_in[1];
    const void* w_in   = d_in[2];
    const void* w_out  = d_in[3];
    const void* conv_w = d_in[4];
    const void* w_ih   = d_in[5];
    const void* w_hh   = d_in[6];
    const void* b_ih   = d_in[7];
    const void* b_hh   = d_in[8];

    const int E   = in_sizes[1] / 2;
    const int nwg = (E + CH - 1) / CH;   // 147 for E=1.2M (<= 256 required)

    // workspace carve-up (256B aligned). Total ~38.4 MB.
    char* ws = (char*)d_ws;
    size_t off = 0;
    auto carve = [&](size_t bytes) {
        void* p = ws + off;
        off += (bytes + 255) & ~(size_t)255;
        return p;
    };
    int*            flags    = (int*)carve(256);
    unsigned short* h1       = (unsigned short*)carve((size_t)N_NODES * H_DIM * 2); // 12.8 MB
    unsigned short* h0       = (unsigned short*)carve((size_t)N_NODES * H_DIM * 2); // 12.8 MB
    int*            counts   = (int*)carve((size_t)N_NODES * 4);
    int*            rowptr   = (int*)carve((size_t)N_NODES * 4);
    int*            wgsorted = (int*)carve((size_t)nwg * CH * 4);                   // 4.8 MB
    int*            lbase_g  = (int*)carve((size_t)nwg * LB_STRIDE * 4);            // 0.46 MB
    int*            esrcP    = (int*)carve((size_t)NBUCK * BCAP * 4);               // 6.4 MB
    unsigned short* winfrag  = (unsigned short*)carve((size_t)16384 * 2);
    unsigned short* wcomb    = (unsigned short*)carve((size_t)4 * 12288 * 2);
    unsigned short* wofrag   = (unsigned short*)carve((size_t)3072 * 2);
    unsigned short* whh_c    = (unsigned short*)carve((size_t)12288 * 2);
    unsigned short* bias_c   = (unsigned short*)carve((size_t)384 * 2);

    // ---- CSR build (kernel 1 also probes dtypes, writes flags) ----
    bucket_local<<<nwg, 256, 0, stream>>>(ei, E, x, wgsorted, lbase_g, flags);
    bucket_csr_prep<<<NBUCK, 256, 0, stream>>>(
        wgsorted, lbase_g, nwg, rowptr, counts, esrcP,
        w_in, w_out, w_hh, b_ih, b_hh, conv_w, w_ih,
        winfrag, wofrag, whh_c, bias_c, wcomb, flags);

    const int gblocks = (ROW_TILES + 3) / 4;  // 1563
    const int lblocks = N_NODES / 16;         // 6250

    // ---- input projection -> h0 ----
    proj_in_kernel<<<gblocks, 256, 0, stream>>>(x, winfrag, h0, flags);

    // ---- GGNN layers, h ping-pong (h0 -> h1 -> h0 -> h1 -> [LDS]) ----
    layer_fused<0><<<lblocks, 256, 0, stream>>>(h0, h1, rowptr, counts, esrcP,
        wcomb + 0 * 12288, whh_c, bias_c, wofrag, d_out, flags);
    layer_fused<0><<<lblocks, 256, 0, stream>>>(h1, h0, rowptr, counts, esrcP,
        wcomb + 1 * 12288, whh_c, bias_c, wofrag, d_out, flags);
    layer_fused<0><<<lblocks, 256, 0, stream>>>(h0, h1, rowptr, counts, esrcP,
        wcomb + 2 * 12288, whh_c, bias_c, wofrag, d_out, flags);
    layer_fused<1><<<lblocks, 256, 0, stream>>>(h1, h0, rowptr, counts, esrcP,
        wcomb + 3 * 12288, whh_c, bias_c, wofrag, d_out, flags);
}